// Round 1
// baseline (287.201 us; speedup 1.0000x reference)
//
#include <hip/hip_runtime.h>
#include <hip/hip_bf16.h>
#include <cstddef>

// Problem constants (SelfAttention: B=4, T=2048, H=16, Dh=64, C=1024)
#define B_  4
#define T_  2048
#define H_  16
#define DH  64
#define C_  1024
#define BH  64    // B_*H_

typedef float  f32x16 __attribute__((ext_vector_type(16)));
typedef __bf16 bf16x8 __attribute__((ext_vector_type(8)));
typedef __bf16 bf16x4 __attribute__((ext_vector_type(4)));

#define MFMA32(a, b, c) __builtin_amdgcn_mfma_f32_32x32x16_bf16(a, b, c, 0, 0, 0)

// mfma_f32_32x32x16_bf16 layouts (cdna4_isa / m74,m101 verified C/D):
//   A[m][k]: m = lane&31, k = (lane>>5)*8 + j   (8 bf16 per lane, b128)
//   B[k][n]: n = lane&31, k = (lane>>5)*8 + j
//   C/D:     col = lane&31, row = (reg&3) + 8*(reg>>2) + 4*(lane>>5)
// All bf16 LDS tiles use row stride 72 (=36 dw == 4 mod 32): fragment b128
// reads rotate bank groups -> conflict-free (measured SQ_LDS_BANK_CONFLICT=0).

__device__ __forceinline__ unsigned cvt_pk_bf16(float lo, float hi) {
    unsigned r;
    asm("v_cvt_pk_bf16_f32 %0, %1, %2" : "=v"(r) : "v"(lo), "v"(hi));
    return r;
}

// ---------------------------------------------------------------------------
// Kernel 1: QKV projection, bf16 MFMA. Block = (128-token tile, one head).
// q is written with scale (1/sqrt(C)) * log2(e) folded so attention can use
// raw v_exp_f32 (exp2) with no per-element multiply.
// ---------------------------------------------------------------------------
__global__ __launch_bounds__(256) void qkv_kernel(
    const float* __restrict__ x,
    const float* __restrict__ Wq, const float* __restrict__ bq,
    const float* __restrict__ Wk, const float* __restrict__ bk,
    const float* __restrict__ Wv, const float* __restrict__ bv,
    __bf16* __restrict__ q, __bf16* __restrict__ k, __bf16* __restrict__ vt)
{
    __shared__ __bf16 Xs[128 * 72];          // x tile [t_local][d], bf16
    __shared__ __bf16 Ws[3][64 * 72];        // W[e][d], bf16
    __bf16* Vtl = Xs;                         // alias: V^T [e][t_local], stride 136

    const int tt  = blockIdx.x;               // 0..15 (128-token tile)
    const int bh  = blockIdx.y;               // 0..63
    const int b   = bh >> 4, h = bh & 15;
    const int t0  = tt * 128;
    const int tid = threadIdx.x;
    const int wave = tid >> 6, lane = tid & 63;
    const int m = lane & 31, hh = lane >> 5;

    // stage x (fp32 -> bf16): 128 rows x 64 cols = 2048 float4 chunks
    #pragma unroll
    for (int i = 0; i < 8; ++i) {
        const int idx = i * 256 + tid;
        const int r = idx >> 4, c = (idx & 15) * 4;
        const float4 x4 = *(const float4*)(x + ((size_t)(b * T_ + t0 + r)) * C_ + h * DH + c);
        const unsigned lo = ((unsigned)__builtin_bit_cast(unsigned short, (__bf16)x4.y) << 16)
                          | (unsigned)__builtin_bit_cast(unsigned short, (__bf16)x4.x);
        const unsigned hi = ((unsigned)__builtin_bit_cast(unsigned short, (__bf16)x4.w) << 16)
                          | (unsigned)__builtin_bit_cast(unsigned short, (__bf16)x4.z);
        *(unsigned*)&Xs[r * 72 + c]     = lo;
        *(unsigned*)&Xs[r * 72 + c + 2] = hi;
    }
    // stage weights (fp32 -> bf16): 3 x 1024 float4 chunks
    #pragma unroll
    for (int i = 0; i < 4; ++i) {
        const int idx = i * 256 + tid;
        const int r = idx >> 4, c = (idx & 15) * 4;
        const float* wsrc[3] = {Wq, Wk, Wv};
        #pragma unroll
        for (int wv_ = 0; wv_ < 3; ++wv_) {
            const float4 w4 = *(const float4*)(wsrc[wv_] + r * 64 + c);
            const unsigned lo = ((unsigned)__builtin_bit_cast(unsigned short, (__bf16)w4.y) << 16)
                              | (unsigned)__builtin_bit_cast(unsigned short, (__bf16)w4.x);
            const unsigned hi = ((unsigned)__builtin_bit_cast(unsigned short, (__bf16)w4.w) << 16)
                              | (unsigned)__builtin_bit_cast(unsigned short, (__bf16)w4.z);
            *(unsigned*)&Ws[wv_][r * 72 + c]     = lo;
            *(unsigned*)&Ws[wv_][r * 72 + c + 2] = hi;
        }
    }
    __syncthreads();

    // hoist x A-fragments (wave-private rows 32*wave + m)
    bf16x8 xf[4];
    #pragma unroll
    for (int ks = 0; ks < 4; ++ks)
        xf[ks] = *(const bf16x8*)&Xs[(wave * 32 + m) * 72 + ks * 16 + hh * 8];
    __syncthreads();   // all frag reads done before Vtl aliases Xs

    // 1/sqrt(1024) * log2(e) folded into q (attention uses exp2 directly)
    const float s32 = 0.03125f * 1.4426950408889634f;

    #pragma unroll
    for (int mat = 0; mat < 3; ++mat) {
        f32x16 acc0 = {}, acc1 = {};
        #pragma unroll
        for (int ks = 0; ks < 4; ++ks) {
            const bf16x8 w0 = *(const bf16x8*)&Ws[mat][(m) * 72 + ks * 16 + hh * 8];
            const bf16x8 w1 = *(const bf16x8*)&Ws[mat][(32 + m) * 72 + ks * 16 + hh * 8];
            acc0 = MFMA32(xf[ks], w0, acc0);
            acc1 = MFMA32(xf[ks], w1, acc1);
        }
        const float* bias = (mat == 0) ? bq : (mat == 1) ? bk : bv;
        const float b0 = bias[m], b1 = bias[32 + m];
        #pragma unroll
        for (int r = 0; r < 16; ++r) {
            const int R = (r & 3) + 8 * (r >> 2) + 4 * hh;   // token row in tile
            const int tloc = wave * 32 + R;
            const float v0 = acc0[r] + b0, v1 = acc1[r] + b1;
            if (mat == 0) {
                const size_t base = ((size_t)bh * T_ + t0 + tloc) * DH;
                q[base + m]      = (__bf16)(v0 * s32);
                q[base + 32 + m] = (__bf16)(v1 * s32);
            } else if (mat == 1) {
                const size_t base = ((size_t)bh * T_ + t0 + tloc) * DH;
                k[base + m]      = (__bf16)v0;
                k[base + 32 + m] = (__bf16)v1;
            } else {
                Vtl[(m) * 136 + tloc]      = (__bf16)v0;   // V^T [e][t_local]
                Vtl[(32 + m) * 136 + tloc] = (__bf16)v1;
            }
        }
    }
    __syncthreads();
    // coalesced vt write: 64 e-rows x 128 t (16B chunks; 1024 chunks / 256 thr)
    #pragma unroll
    for (int i = 0; i < 4; ++i) {
        const int idx = i * 256 + tid;
        const int e = idx >> 4, c = (idx & 15) * 8;
        *(uint4*)(vt + ((size_t)(bh * 64 + e)) * T_ + t0 + c) = *(uint4*)&Vtl[e * 136 + c];
    }
}

// ---------------------------------------------------------------------------
// Kernel 2: flash attention, swapped-operand (T12) + async-STAGE (T14).
// Block = (128-query tile, bh), 4 waves, each owns 32 q-rows.
//   S^T = mfma(K, Q): lane holds P^T[kv 0..31][q=lane&31] per accumulator
//   -> softmax fully in-register (exp2; log2e pre-folded into q)
//   -> PV B-fragments built via v_cvt_pk_bf16_f32 + v_permlane32_swap_b32
//   O^T = mfma(V^T, P^T) accumulates [d][q]; l = per-lane sum + 1 shfl_xor(32).
// No P LDS buffer (LDS 18.4 KB). Next K/V tile global loads issued before
// compute, LDS-written after the tail barrier (latency hidden under MFMA).
// ---------------------------------------------------------------------------
__global__ __launch_bounds__(256, 4) void attn_kernel(
    const __bf16* __restrict__ q, const __bf16* __restrict__ k,
    const __bf16* __restrict__ vt, __bf16* __restrict__ o)
{
    __shared__ __bf16 Ks[64 * 72];      // K tile [k_row][d]
    __shared__ __bf16 Vts[64 * 72];     // V^T tile [d][k_row]

    const int bh  = blockIdx.y;
    const int q0  = blockIdx.x * 128;
    const int tid = threadIdx.x;
    const int wave = tid >> 6, lane = tid & 63;
    const int m = lane & 31, h = lane >> 5;
    const int qrow0 = wave * 32;

    const __bf16* qb = q  + (size_t)bh * T_ * DH;
    const __bf16* kb = k  + (size_t)bh * T_ * DH;
    const __bf16* vb = vt + (size_t)bh * DH * T_;

    // Q fragments straight from global: row q0+qrow0+m, 4 x 16B per lane.
    // (B-operand of S^T: B[k=d][n=q] = Q[q][d] -> identical addressing.)
    bf16x8 qf[4];
    #pragma unroll
    for (int ks = 0; ks < 4; ++ks)
        qf[ks] = *(const bf16x8*)(qb + (size_t)(q0 + qrow0 + m) * DH + ks * 16 + h * 8);

    // staging geometry: 256 threads cover 64x64 bf16 in 2 uint4 each
    const int r0s = tid >> 3;           // 0..31
    const int c0s = (tid & 7) * 8;      // 0,8,..,56

    uint4 kreg[2], vreg[2];
    #pragma unroll
    for (int i = 0; i < 2; ++i) {
        kreg[i] = *(const uint4*)(kb + (size_t)(r0s + 32 * i) * DH + c0s);
        vreg[i] = *(const uint4*)(vb + (size_t)(r0s + 32 * i) * T_ + c0s);
    }
    #pragma unroll
    for (int i = 0; i < 2; ++i) {
        *(uint4*)&Ks[(r0s + 32 * i) * 72 + c0s]  = kreg[i];
        *(uint4*)&Vts[(r0s + 32 * i) * 72 + c0s] = vreg[i];
    }

    f32x16 O0 = {}, O1 = {};
    float lsum = 0.f;

    for (int kt = 0; kt < T_; kt += 64) {
        __syncthreads();                       // staged tile visible
        const bool pre = (kt + 64 < T_);
        if (pre) {                             // T14: issue next-tile loads now
            #pragma unroll
            for (int i = 0; i < 2; ++i) {
                kreg[i] = *(const uint4*)(kb + (size_t)(kt + 64 + r0s + 32 * i) * DH + c0s);
                vreg[i] = *(const uint4*)(vb + (size_t)(r0s + 32 * i) * T_ + kt + 64 + c0s);
            }
        }

        // S^T = K Q^T : A = K rows (kv), B = Q rows (q). Same LDS addressing
        // as unswapped, only operand order changes.
        f32x16 S0 = {}, S1 = {};
        #pragma unroll
        for (int ks = 0; ks < 4; ++ks) {
            const bf16x8 k0 = *(const bf16x8*)&Ks[(m) * 72 + ks * 16 + h * 8];
            const bf16x8 k1 = *(const bf16x8*)&Ks[(32 + m) * 72 + ks * 16 + h * 8];
            S0 = MFMA32(k0, qf[ks], S0);
            S1 = MFMA32(k1, qf[ks], S1);
        }

        // Per 16-kv chunk: exp2 -> pack bf16 pairs -> permlane32_swap builds
        // the B-fragment (k = h*8+j), then 2 PV MFMAs. All in-register.
        // Row map: reg r of an S-half is kv row (r&3) + 8*(r>>2) + 4h.
        #pragma unroll
        for (int c = 0; c < 4; ++c) {
            const f32x16 Sh = (c < 2) ? S0 : S1;
            const int rb = (c & 1) * 8;
            float e0 = __builtin_amdgcn_exp2f(Sh[rb + 0]);
            float e1 = __builtin_amdgcn_exp2f(Sh[rb + 1]);
            float e2 = __builtin_amdgcn_exp2f(Sh[rb + 2]);
            float e3 = __builtin_amdgcn_exp2f(Sh[rb + 3]);
            float e4 = __builtin_amdgcn_exp2f(Sh[rb + 4]);
            float e5 = __builtin_amdgcn_exp2f(Sh[rb + 5]);
            float e6 = __builtin_amdgcn_exp2f(Sh[rb + 6]);
            float e7 = __builtin_amdgcn_exp2f(Sh[rb + 7]);
            lsum += ((e0 + e1) + (e2 + e3)) + ((e4 + e5) + (e6 + e7));
            unsigned a0 = cvt_pk_bf16(e0, e1);
            unsigned a1 = cvt_pk_bf16(e2, e3);
            unsigned b0 = cvt_pk_bf16(e4, e5);
            unsigned b1 = cvt_pk_bf16(e6, e7);
            // swap: a' = {a.lo32, b.lo32partner}, b' = {a.hi32partner, b.hi32}
            asm("v_permlane32_swap_b32 %0, %1" : "+v"(a0), "+v"(b0));
            asm("v_permlane32_swap_b32 %0, %1" : "+v"(a1), "+v"(b1));
            const uint4 pw = {a0, a1, b0, b1};
            const bf16x8 pb = __builtin_bit_cast(bf16x8, pw);
            const bf16x8 va0 = *(const bf16x8*)&Vts[(m) * 72 + c * 16 + h * 8];
            const bf16x8 va1 = *(const bf16x8*)&Vts[(32 + m) * 72 + c * 16 + h * 8];
            O0 = MFMA32(va0, pb, O0);   // O^T[d 0..31][q]
            O1 = MFMA32(va1, pb, O1);   // O^T[d 32..63][q]
        }

        __syncthreads();                       // all reads of this tile done
        if (pre) {                             // land next tile
            #pragma unroll
            for (int i = 0; i < 2; ++i) {
                *(uint4*)&Ks[(r0s + 32 * i) * 72 + c0s]  = kreg[i];
                *(uint4*)&Vts[(r0s + 32 * i) * 72 + c0s] = vreg[i];
            }
        }
    }

    // l[q]: lane l and l+32 hold complementary kv halves of the same q
    lsum += __shfl_xor(lsum, 32);
    const float linv = 1.0f / lsum;

    // O^T write: lane owns one q-row; reg r -> d = (r&3) + 8*(r>>2) + 4h,
    // so each group of 4 regs is 4 consecutive d -> 8B packed stores.
    __bf16* ob = o + ((size_t)bh * T_ + q0 + qrow0 + m) * DH;
    #pragma unroll
    for (int g = 0; g < 4; ++g) {
        bf16x4 w0, w1;
        #pragma unroll
        for (int j = 0; j < 4; ++j) {
            w0[j] = (__bf16)(O0[4 * g + j] * linv);
            w1[j] = (__bf16)(O1[4 * g + j] * linv);
        }
        *(bf16x4*)(ob + 8 * g + 4 * h)      = w0;
        *(bf16x4*)(ob + 32 + 8 * g + 4 * h) = w1;
    }
}

// ---------------------------------------------------------------------------
// Kernel 3: output projection, bf16 MFMA. out[tok][e] = A[tok][:] . Wp[e][:] + bp
// Block = 128 tokens x 128 e-cols; K-chunks of 64 (== one head of A).
// ---------------------------------------------------------------------------
__global__ __launch_bounds__(256) void proj_kernel(
    const __bf16* __restrict__ a,      // [bh][t][d]
    const float* __restrict__ Wp, const float* __restrict__ bp,
    float* __restrict__ out)
{
    __shared__ __bf16 As[128 * 72];
    __shared__ __bf16 Bs[128 * 72];

    const int tb = blockIdx.x, eb = blockIdx.y;
    const int tid = threadIdx.x;
    const int wave = tid >> 6, lane = tid & 63;
    const int m = lane & 31, h = lane >> 5;
    const int tok0 = tb * 128;
    const int b = tok0 >> 11, t0 = tok0 & (T_ - 1);
    const int e0 = eb * 128;

    f32x16 acc[4] = {f32x16{}, f32x16{}, f32x16{}, f32x16{}};

    for (int cb = 0; cb < 16; ++cb) {
        __syncthreads();
        // As: 128 rows x 64 bf16 (head cb of A), direct bf16 copy
        #pragma unroll
        for (int i = 0; i < 4; ++i) {
            const int idx = i * 256 + tid;
            const int r = idx >> 3, c = (idx & 7) * 8;
            *(uint4*)&As[r * 72 + c] =
                *(const uint4*)(a + ((size_t)(b * H_ + cb) * T_ + t0 + r) * DH + c);
        }
        // Bs: Wp rows e0+r, cols cb*64.., fp32 -> bf16
        #pragma unroll
        for (int i = 0; i < 8; ++i) {
            const int idx = i * 256 + tid;
            const int r = idx >> 4, c = (idx & 15) * 4;
            const float4 w4 = *(const float4*)(Wp + (size_t)(e0 + r) * C_ + cb * 64 + c);
            const unsigned lo = ((unsigned)__builtin_bit_cast(unsigned short, (__bf16)w4.y) << 16)
                              | (unsigned)__builtin_bit_cast(unsigned short, (__bf16)w4.x);
            const unsigned hi = ((unsigned)__builtin_bit_cast(unsigned short, (__bf16)w4.w) << 16)
                              | (unsigned)__builtin_bit_cast(unsigned short, (__bf16)w4.z);
            *(unsigned*)&Bs[r * 72 + c]     = lo;
            *(unsigned*)&Bs[r * 72 + c + 2] = hi;
        }
        __syncthreads();

        #pragma unroll
        for (int ks = 0; ks < 4; ++ks) {
            const bf16x8 af = *(const bf16x8*)&As[(wave * 32 + m) * 72 + ks * 16 + h * 8];
            #pragma unroll
            for (int n = 0; n < 4; ++n) {
                const bf16x8 bf = *(const bf16x8*)&Bs[(n * 32 + m) * 72 + ks * 16 + h * 8];
                acc[n] = MFMA32(af, bf, acc[n]);
            }
        }
    }

    #pragma unroll
    for (int n = 0; n < 4; ++n) {
        const int e = e0 + n * 32 + m;
        const float bias = bp[e];
        #pragma unroll
        for (int r = 0; r < 16; ++r) {
            const int R = (r & 3) + 8 * (r >> 2) + 4 * h;
            out[(size_t)(tok0 + wave * 32 + R) * C_ + e] = acc[n][r] + bias;
        }
    }
}

// ---------------------------------------------------------------------------
// Workspace (bf16): q | k | vt | attn_out, each B*H*T*DH = 8388608 elems
// -> 64 MiB total.
// ---------------------------------------------------------------------------
extern "C" void kernel_launch(void* const* d_in, const int* in_sizes, int n_in,
                              void* d_out, int out_size, void* d_ws, size_t ws_size,
                              hipStream_t stream)
{
    const float* x  = (const float*)d_in[0];
    const float* Wq = (const float*)d_in[1];
    const float* bq = (const float*)d_in[2];
    const float* Wk = (const float*)d_in[3];
    const float* bk = (const float*)d_in[4];
    const float* Wv = (const float*)d_in[5];
    const float* bv = (const float*)d_in[6];
    const float* Wp = (const float*)d_in[7];
    const float* bp = (const float*)d_in[8];

    const size_t N = (size_t)BH * T_ * DH;
    __bf16* qws  = (__bf16*)d_ws;
    __bf16* kws  = qws + N;
    __bf16* vtws = kws + N;
    __bf16* ows  = vtws + N;

    qkv_kernel<<<dim3(16, 64), 256, 0, stream>>>(
        x, Wq, bq, Wk, bk, Wv, bv, qws, kws, vtws);
    attn_kernel<<<dim3(16, 64), 256, 0, stream>>>(qws, kws, vtws, ows);
    proj_kernel<<<dim3(64, 8), 256, 0, stream>>>(ows, Wp, bp, (float*)d_out);
}

// Round 2
// 247.325 us; speedup vs baseline: 1.1612x; 1.1612x over previous
//
#include <hip/hip_runtime.h>
#include <hip/hip_bf16.h>
#include <cstddef>

// Problem constants (SelfAttention: B=4, T=2048, H=16, Dh=64, C=1024)
#define B_  4
#define T_  2048
#define H_  16
#define DH  64
#define C_  1024
#define BH  64    // B_*H_

typedef float  f32x16 __attribute__((ext_vector_type(16)));
typedef __bf16 bf16x8 __attribute__((ext_vector_type(8)));
typedef __bf16 bf16x4 __attribute__((ext_vector_type(4)));

#define MFMA32(a, b, c) __builtin_amdgcn_mfma_f32_32x32x16_bf16(a, b, c, 0, 0, 0)

// mfma_f32_32x32x16_bf16 layouts (cdna4_isa / m74,m101 verified C/D):
//   A[m][k]: m = lane&31, k = (lane>>5)*8 + j   (8 bf16 per lane, b128)
//   B[k][n]: n = lane&31, k = (lane>>5)*8 + j
//   C/D:     col = lane&31, row = (reg&3) + 8*(reg>>2) + 4*(lane>>5)
// All bf16 LDS tiles use row stride 72 (=36 dw == 4 mod 32): fragment b128
// reads rotate bank groups -> conflict-free (measured SQ_LDS_BANK_CONFLICT=0).

__device__ __forceinline__ unsigned cvt_pk_bf16(float lo, float hi) {
    unsigned r;
    asm("v_cvt_pk_bf16_f32 %0, %1, %2" : "=v"(r) : "v"(lo), "v"(hi));
    return r;
}

// ---------------------------------------------------------------------------
// Kernel 1: QKV projection, bf16 MFMA. Block = (128-token tile, one head).
// q is written with scale (1/sqrt(C)) * log2(e) folded so attention can use
// raw v_exp_f32 (exp2) with no per-element multiply.
// ---------------------------------------------------------------------------
__global__ __launch_bounds__(256) void qkv_kernel(
    const float* __restrict__ x,
    const float* __restrict__ Wq, const float* __restrict__ bq,
    const float* __restrict__ Wk, const float* __restrict__ bk,
    const float* __restrict__ Wv, const float* __restrict__ bv,
    __bf16* __restrict__ q, __bf16* __restrict__ k, __bf16* __restrict__ vt)
{
    __shared__ __bf16 Xs[128 * 72];          // x tile [t_local][d], bf16
    __shared__ __bf16 Ws[3][64 * 72];        // W[e][d], bf16
    __bf16* Vtl = Xs;                         // alias: V^T [e][t_local], stride 136

    const int tt  = blockIdx.x;               // 0..15 (128-token tile)
    const int bh  = blockIdx.y;               // 0..63
    const int b   = bh >> 4, h = bh & 15;
    const int t0  = tt * 128;
    const int tid = threadIdx.x;
    const int wave = tid >> 6, lane = tid & 63;
    const int m = lane & 31, hh = lane >> 5;

    // stage x (fp32 -> bf16): 128 rows x 64 cols = 2048 float4 chunks
    #pragma unroll
    for (int i = 0; i < 8; ++i) {
        const int idx = i * 256 + tid;
        const int r = idx >> 4, c = (idx & 15) * 4;
        const float4 x4 = *(const float4*)(x + ((size_t)(b * T_ + t0 + r)) * C_ + h * DH + c);
        const unsigned lo = ((unsigned)__builtin_bit_cast(unsigned short, (__bf16)x4.y) << 16)
                          | (unsigned)__builtin_bit_cast(unsigned short, (__bf16)x4.x);
        const unsigned hi = ((unsigned)__builtin_bit_cast(unsigned short, (__bf16)x4.w) << 16)
                          | (unsigned)__builtin_bit_cast(unsigned short, (__bf16)x4.z);
        *(unsigned*)&Xs[r * 72 + c]     = lo;
        *(unsigned*)&Xs[r * 72 + c + 2] = hi;
    }
    // stage weights (fp32 -> bf16): 3 x 1024 float4 chunks
    #pragma unroll
    for (int i = 0; i < 4; ++i) {
        const int idx = i * 256 + tid;
        const int r = idx >> 4, c = (idx & 15) * 4;
        const float* wsrc[3] = {Wq, Wk, Wv};
        #pragma unroll
        for (int wv_ = 0; wv_ < 3; ++wv_) {
            const float4 w4 = *(const float4*)(wsrc[wv_] + r * 64 + c);
            const unsigned lo = ((unsigned)__builtin_bit_cast(unsigned short, (__bf16)w4.y) << 16)
                              | (unsigned)__builtin_bit_cast(unsigned short, (__bf16)w4.x);
            const unsigned hi = ((unsigned)__builtin_bit_cast(unsigned short, (__bf16)w4.w) << 16)
                              | (unsigned)__builtin_bit_cast(unsigned short, (__bf16)w4.z);
            *(unsigned*)&Ws[wv_][r * 72 + c]     = lo;
            *(unsigned*)&Ws[wv_][r * 72 + c + 2] = hi;
        }
    }
    __syncthreads();

    // hoist x A-fragments (wave-private rows 32*wave + m)
    bf16x8 xf[4];
    #pragma unroll
    for (int ks = 0; ks < 4; ++ks)
        xf[ks] = *(const bf16x8*)&Xs[(wave * 32 + m) * 72 + ks * 16 + hh * 8];
    __syncthreads();   // all frag reads done before Vtl aliases Xs

    // 1/sqrt(1024) * log2(e) folded into q (attention uses exp2 directly)
    const float s32 = 0.03125f * 1.4426950408889634f;

    #pragma unroll
    for (int mat = 0; mat < 3; ++mat) {
        f32x16 acc0 = {}, acc1 = {};
        #pragma unroll
        for (int ks = 0; ks < 4; ++ks) {
            const bf16x8 w0 = *(const bf16x8*)&Ws[mat][(m) * 72 + ks * 16 + hh * 8];
            const bf16x8 w1 = *(const bf16x8*)&Ws[mat][(32 + m) * 72 + ks * 16 + hh * 8];
            acc0 = MFMA32(xf[ks], w0, acc0);
            acc1 = MFMA32(xf[ks], w1, acc1);
        }
        const float* bias = (mat == 0) ? bq : (mat == 1) ? bk : bv;
        const float b0 = bias[m], b1 = bias[32 + m];
        #pragma unroll
        for (int r = 0; r < 16; ++r) {
            const int R = (r & 3) + 8 * (r >> 2) + 4 * hh;   // token row in tile
            const int tloc = wave * 32 + R;
            const float v0 = acc0[r] + b0, v1 = acc1[r] + b1;
            if (mat == 0) {
                const size_t base = ((size_t)bh * T_ + t0 + tloc) * DH;
                q[base + m]      = (__bf16)(v0 * s32);
                q[base + 32 + m] = (__bf16)(v1 * s32);
            } else if (mat == 1) {
                const size_t base = ((size_t)bh * T_ + t0 + tloc) * DH;
                k[base + m]      = (__bf16)v0;
                k[base + 32 + m] = (__bf16)v1;
            } else {
                Vtl[(m) * 136 + tloc]      = (__bf16)v0;   // V^T [e][t_local]
                Vtl[(32 + m) * 136 + tloc] = (__bf16)v1;
            }
        }
    }
    __syncthreads();
    // coalesced vt write: 64 e-rows x 128 t (16B chunks; 1024 chunks / 256 thr)
    #pragma unroll
    for (int i = 0; i < 4; ++i) {
        const int idx = i * 256 + tid;
        const int e = idx >> 4, c = (idx & 15) * 8;
        *(uint4*)(vt + ((size_t)(bh * 64 + e)) * T_ + t0 + c) = *(uint4*)&Vtl[e * 136 + c];
    }
}

// ---------------------------------------------------------------------------
// Kernel 2: flash attention, swapped-operand in-register softmax.
// Block = (256-query tile, bh), 4 waves; EACH WAVE OWNS 64 q-rows (2 halves)
// so K/V LDS fragments are reused across both halves: 24 ds_read_b128 per
// 32 MFMA (LDS pipe demand 0.75x matrix pipe, vs 1:1 at 32 rows/wave).
// Double-buffered K/V tiles, ONE barrier per kv-tile; next-tile global loads
// issued before compute (latency hidden under MFMA+softmax).
// Epilogue: O^T -> LDS transpose -> fully coalesced 16B global stores
// (fixes the 280 MB partial-line write amplification of the O^T layout).
// ---------------------------------------------------------------------------
__global__ __launch_bounds__(256, 2) void attn_kernel(
    const __bf16* __restrict__ q, const __bf16* __restrict__ k,
    const __bf16* __restrict__ vt, __bf16* __restrict__ o)
{
    __shared__ __bf16 smem[2][2][64 * 72];   // [buf][K=0/V^T=1][row][d], 36.9 KB

    const int bh  = blockIdx.y;
    const int q0  = blockIdx.x * 256;
    const int tid = threadIdx.x;
    const int wave = tid >> 6, lane = tid & 63;
    const int m = lane & 31, h = lane >> 5;

    const __bf16* qb = q  + (size_t)bh * T_ * DH;
    const __bf16* kb = k  + (size_t)bh * T_ * DH;
    const __bf16* vb = vt + (size_t)bh * DH * T_;

    // Q fragments straight from global: 2 halves x 4 ks (one-time, L2-served)
    bf16x8 qf[2][4];
    #pragma unroll
    for (int hf = 0; hf < 2; ++hf)
        #pragma unroll
        for (int ks = 0; ks < 4; ++ks)
            qf[hf][ks] = *(const bf16x8*)(qb +
                (size_t)(q0 + wave * 64 + hf * 32 + m) * DH + ks * 16 + h * 8);

    // staging geometry: 256 threads cover 64x64 bf16 in 2 uint4 each
    const int r0s = tid >> 3;           // 0..31
    const int c0s = (tid & 7) * 8;      // 0,8,..,56

    uint4 kreg[2], vreg[2];
    #pragma unroll
    for (int i = 0; i < 2; ++i) {
        kreg[i] = *(const uint4*)(kb + (size_t)(r0s + 32 * i) * DH + c0s);
        vreg[i] = *(const uint4*)(vb + (size_t)(r0s + 32 * i) * T_ + c0s);
    }
    #pragma unroll
    for (int i = 0; i < 2; ++i) {
        *(uint4*)&smem[0][0][(r0s + 32 * i) * 72 + c0s] = kreg[i];
        *(uint4*)&smem[0][1][(r0s + 32 * i) * 72 + c0s] = vreg[i];
    }

    f32x16 O00 = {}, O01 = {}, O10 = {}, O11 = {};   // [half][d-half], O^T [d][q]
    float ls0 = 0.f, ls1 = 0.f;

    int cur = 0;
    for (int kt = 0; kt < T_; kt += 64) {
        __syncthreads();                       // buf[cur] fully staged
        const bool pre = (kt + 64 < T_);
        if (pre) {                             // issue next-tile loads now
            #pragma unroll
            for (int i = 0; i < 2; ++i) {
                kreg[i] = *(const uint4*)(kb + (size_t)(kt + 64 + r0s + 32 * i) * DH + c0s);
                vreg[i] = *(const uint4*)(vb + (size_t)(r0s + 32 * i) * T_ + kt + 64 + c0s);
            }
        }
        const __bf16* Ksb  = &smem[cur][0][0];
        const __bf16* Vtsb = &smem[cur][1][0];

        // V fragments once per tile, reused by both q-halves
        bf16x8 vf0[4], vf1[4];
        #pragma unroll
        for (int c = 0; c < 4; ++c) {
            vf0[c] = *(const bf16x8*)&Vtsb[(m) * 72 + c * 16 + h * 8];
            vf1[c] = *(const bf16x8*)&Vtsb[(32 + m) * 72 + c * 16 + h * 8];
        }

        #pragma unroll
        for (int hf = 0; hf < 2; ++hf) {
            // S^T = K Q^T for this 32-row q-half
            f32x16 S0 = {}, S1 = {};
            #pragma unroll
            for (int ks = 0; ks < 4; ++ks) {
                const bf16x8 k0 = *(const bf16x8*)&Ksb[(m) * 72 + ks * 16 + h * 8];
                const bf16x8 k1 = *(const bf16x8*)&Ksb[(32 + m) * 72 + ks * 16 + h * 8];
                S0 = MFMA32(k0, qf[hf][ks], S0);
                S1 = MFMA32(k1, qf[hf][ks], S1);
            }

            float lsum = 0.f;
            #pragma unroll
            for (int c = 0; c < 4; ++c) {
                const f32x16 Sh = (c < 2) ? S0 : S1;
                const int rb = (c & 1) * 8;
                float e0 = __builtin_amdgcn_exp2f(Sh[rb + 0]);
                float e1 = __builtin_amdgcn_exp2f(Sh[rb + 1]);
                float e2 = __builtin_amdgcn_exp2f(Sh[rb + 2]);
                float e3 = __builtin_amdgcn_exp2f(Sh[rb + 3]);
                float e4 = __builtin_amdgcn_exp2f(Sh[rb + 4]);
                float e5 = __builtin_amdgcn_exp2f(Sh[rb + 5]);
                float e6 = __builtin_amdgcn_exp2f(Sh[rb + 6]);
                float e7 = __builtin_amdgcn_exp2f(Sh[rb + 7]);
                lsum += ((e0 + e1) + (e2 + e3)) + ((e4 + e5) + (e6 + e7));
                unsigned a0 = cvt_pk_bf16(e0, e1);
                unsigned a1 = cvt_pk_bf16(e2, e3);
                unsigned b0 = cvt_pk_bf16(e4, e5);
                unsigned b1 = cvt_pk_bf16(e6, e7);
                asm("v_permlane32_swap_b32 %0, %1" : "+v"(a0), "+v"(b0));
                asm("v_permlane32_swap_b32 %0, %1" : "+v"(a1), "+v"(b1));
                const uint4 pw = {a0, a1, b0, b1};
                const bf16x8 pb = __builtin_bit_cast(bf16x8, pw);
                if (hf == 0) {
                    O00 = MFMA32(vf0[c], pb, O00);
                    O01 = MFMA32(vf1[c], pb, O01);
                } else {
                    O10 = MFMA32(vf0[c], pb, O10);
                    O11 = MFMA32(vf1[c], pb, O11);
                }
            }
            if (hf == 0) ls0 += lsum; else ls1 += lsum;
        }

        if (pre) {                             // land next tile into buf^1
            #pragma unroll
            for (int i = 0; i < 2; ++i) {
                *(uint4*)&smem[cur ^ 1][0][(r0s + 32 * i) * 72 + c0s] = kreg[i];
                *(uint4*)&smem[cur ^ 1][1][(r0s + 32 * i) * 72 + c0s] = vreg[i];
            }
        }
        cur ^= 1;
    }

    // l[q]: lanes l and l+32 hold complementary kv halves of the same q-row
    ls0 += __shfl_xor(ls0, 32);
    ls1 += __shfl_xor(ls1, 32);
    const float li0 = 1.0f / ls0, li1 = 1.0f / ls1;

    __syncthreads();                            // all K/V reads done; reuse smem
    __bf16* Os = &smem[0][0][0];                // [256 rows][stride 72]

    // O^T -> LDS: lane owns q-rows (wave*64 + m) and (wave*64 + 32 + m).
    // reg r -> d = (r&3) + 8*(r>>2) + 4h: each group of 4 regs = 4 consecutive d.
    #pragma unroll
    for (int g = 0; g < 4; ++g) {
        bf16x4 w00, w01, w10, w11;
        #pragma unroll
        for (int j = 0; j < 4; ++j) {
            w00[j] = (__bf16)(O00[4 * g + j] * li0);
            w01[j] = (__bf16)(O01[4 * g + j] * li0);
            w10[j] = (__bf16)(O10[4 * g + j] * li1);
            w11[j] = (__bf16)(O11[4 * g + j] * li1);
        }
        const int row0 = (wave * 64 + m) * 72;
        const int row1 = (wave * 64 + 32 + m) * 72;
        *(bf16x4*)&Os[row0 + 8 * g + 4 * h]      = w00;
        *(bf16x4*)&Os[row0 + 32 + 8 * g + 4 * h] = w01;
        *(bf16x4*)&Os[row1 + 8 * g + 4 * h]      = w10;
        *(bf16x4*)&Os[row1 + 32 + 8 * g + 4 * h] = w11;
    }
    __syncthreads();

    // fully coalesced store: 256 rows x 64 bf16 = 2048 uint4 / 256 threads
    __bf16* ob = o + ((size_t)bh * T_ + q0) * DH;
    #pragma unroll
    for (int i = 0; i < 8; ++i) {
        const int idx = i * 256 + tid;
        const int r = idx >> 3, c = (idx & 7) * 8;
        *(uint4*)(ob + (size_t)r * DH + c) = *(uint4*)&Os[r * 72 + c];
    }
}

// ---------------------------------------------------------------------------
// Kernel 3: output projection, bf16 MFMA. out[tok][e] = A[tok][:] . Wp[e][:] + bp
// Block = 128 tokens x 128 e-cols; K-chunks of 64 (== one head of A).
// ---------------------------------------------------------------------------
__global__ __launch_bounds__(256) void proj_kernel(
    const __bf16* __restrict__ a,      // [bh][t][d]
    const float* __restrict__ Wp, const float* __restrict__ bp,
    float* __restrict__ out)
{
    __shared__ __bf16 As[128 * 72];
    __shared__ __bf16 Bs[128 * 72];

    const int tb = blockIdx.x, eb = blockIdx.y;
    const int tid = threadIdx.x;
    const int wave = tid >> 6, lane = tid & 63;
    const int m = lane & 31, h = lane >> 5;
    const int tok0 = tb * 128;
    const int b = tok0 >> 11, t0 = tok0 & (T_ - 1);
    const int e0 = eb * 128;

    f32x16 acc[4] = {f32x16{}, f32x16{}, f32x16{}, f32x16{}};

    for (int cb = 0; cb < 16; ++cb) {
        __syncthreads();
        // As: 128 rows x 64 bf16 (head cb of A), direct bf16 copy
        #pragma unroll
        for (int i = 0; i < 4; ++i) {
            const int idx = i * 256 + tid;
            const int r = idx >> 3, c = (idx & 7) * 8;
            *(uint4*)&As[r * 72 + c] =
                *(const uint4*)(a + ((size_t)(b * H_ + cb) * T_ + t0 + r) * DH + c);
        }
        // Bs: Wp rows e0+r, cols cb*64.., fp32 -> bf16
        #pragma unroll
        for (int i = 0; i < 8; ++i) {
            const int idx = i * 256 + tid;
            const int r = idx >> 4, c = (idx & 15) * 4;
            const float4 w4 = *(const float4*)(Wp + (size_t)(e0 + r) * C_ + cb * 64 + c);
            const unsigned lo = ((unsigned)__builtin_bit_cast(unsigned short, (__bf16)w4.y) << 16)
                              | (unsigned)__builtin_bit_cast(unsigned short, (__bf16)w4.x);
            const unsigned hi = ((unsigned)__builtin_bit_cast(unsigned short, (__bf16)w4.w) << 16)
                              | (unsigned)__builtin_bit_cast(unsigned short, (__bf16)w4.z);
            *(unsigned*)&Bs[r * 72 + c]     = lo;
            *(unsigned*)&Bs[r * 72 + c + 2] = hi;
        }
        __syncthreads();

        #pragma unroll
        for (int ks = 0; ks < 4; ++ks) {
            const bf16x8 af = *(const bf16x8*)&As[(wave * 32 + m) * 72 + ks * 16 + h * 8];
            #pragma unroll
            for (int n = 0; n < 4; ++n) {
                const bf16x8 bf = *(const bf16x8*)&Bs[(n * 32 + m) * 72 + ks * 16 + h * 8];
                acc[n] = MFMA32(af, bf, acc[n]);
            }
        }
    }

    #pragma unroll
    for (int n = 0; n < 4; ++n) {
        const int e = e0 + n * 32 + m;
        const float bias = bp[e];
        #pragma unroll
        for (int r = 0; r < 16; ++r) {
            const int R = (r & 3) + 8 * (r >> 2) + 4 * h;
            out[(size_t)(tok0 + wave * 32 + R) * C_ + e] = acc[n][r] + bias;
        }
    }
}

// ---------------------------------------------------------------------------
// Workspace (bf16): q | k | vt | attn_out, each B*H*T*DH = 8388608 elems
// -> 64 MiB total.
// ---------------------------------------------------------------------------
extern "C" void kernel_launch(void* const* d_in, const int* in_sizes, int n_in,
                              void* d_out, int out_size, void* d_ws, size_t ws_size,
                              hipStream_t stream)
{
    const float* x  = (const float*)d_in[0];
    const float* Wq = (const float*)d_in[1];
    const float* bq = (const float*)d_in[2];
    const float* Wk = (const float*)d_in[3];
    const float* bk = (const float*)d_in[4];
    const float* Wv = (const float*)d_in[5];
    const float* bv = (const float*)d_in[6];
    const float* Wp = (const float*)d_in[7];
    const float* bp = (const float*)d_in[8];

    const size_t N = (size_t)BH * T_ * DH;
    __bf16* qws  = (__bf16*)d_ws;
    __bf16* kws  = qws + N;
    __bf16* vtws = kws + N;
    __bf16* ows  = vtws + N;

    qkv_kernel<<<dim3(16, 64), 256, 0, stream>>>(
        x, Wq, bq, Wk, bk, Wv, bv, qws, kws, vtws);
    attn_kernel<<<dim3(8, 64), 256, 0, stream>>>(qws, kws, vtws, ows);
    proj_kernel<<<dim3(64, 8), 256, 0, stream>>>(ows, Wp, bp, (float*)d_out);
}

// Round 3
// 229.531 us; speedup vs baseline: 1.2513x; 1.0775x over previous
//
#include <hip/hip_runtime.h>
#include <hip/hip_bf16.h>
#include <cstddef>

// Problem constants (SelfAttention: B=4, T=2048, H=16, Dh=64, C=1024)
#define B_  4
#define T_  2048
#define H_  16
#define DH  64
#define C_  1024
#define BH  64    // B_*H_

typedef float  f32x16 __attribute__((ext_vector_type(16)));
typedef __bf16 bf16x8 __attribute__((ext_vector_type(8)));
typedef __bf16 bf16x4 __attribute__((ext_vector_type(4)));

#define MFMA32(a, b, c) __builtin_amdgcn_mfma_f32_32x32x16_bf16(a, b, c, 0, 0, 0)

// mfma_f32_32x32x16_bf16 layouts (cdna4_isa / m74,m101 verified C/D):
//   A[m][k]: m = lane&31, k = (lane>>5)*8 + j   (8 bf16 per lane, b128)
//   B[k][n]: n = lane&31, k = (lane>>5)*8 + j
//   C/D:     col = lane&31, row = (reg&3) + 8*(reg>>2) + 4*(lane>>5)
// All bf16 LDS tiles use row stride 72 (=36 dw == 4 mod 32): fragment b128
// reads rotate bank groups -> conflict-free (measured SQ_LDS_BANK_CONFLICT~0).

__device__ __forceinline__ unsigned cvt_pk_bf16(float lo, float hi) {
    unsigned r;
    asm("v_cvt_pk_bf16_f32 %0, %1, %2" : "=v"(r) : "v"(lo), "v"(hi));
    return r;
}

// ---------------------------------------------------------------------------
// Kernel 1: QKV projection, bf16 MFMA. Block = (128-token tile, one head).
// q is written with scale (1/sqrt(C)) * log2(e) folded so attention can use
// raw v_exp_f32 (exp2) with no per-element multiply.
// ---------------------------------------------------------------------------
__global__ __launch_bounds__(256) void qkv_kernel(
    const float* __restrict__ x,
    const float* __restrict__ Wq, const float* __restrict__ bq,
    const float* __restrict__ Wk, const float* __restrict__ bk,
    const float* __restrict__ Wv, const float* __restrict__ bv,
    __bf16* __restrict__ q, __bf16* __restrict__ k, __bf16* __restrict__ vt)
{
    __shared__ __bf16 Xs[128 * 72];          // x tile [t_local][d], bf16
    __shared__ __bf16 Ws[3][64 * 72];        // W[e][d], bf16
    __bf16* Vtl = Xs;                         // alias: V^T [e][t_local], stride 136

    const int tt  = blockIdx.x;               // 0..15 (128-token tile)
    const int bh  = blockIdx.y;               // 0..63
    const int b   = bh >> 4, h = bh & 15;
    const int t0  = tt * 128;
    const int tid = threadIdx.x;
    const int wave = tid >> 6, lane = tid & 63;
    const int m = lane & 31, hh = lane >> 5;

    // stage x (fp32 -> bf16): 128 rows x 64 cols = 2048 float4 chunks
    #pragma unroll
    for (int i = 0; i < 8; ++i) {
        const int idx = i * 256 + tid;
        const int r = idx >> 4, c = (idx & 15) * 4;
        const float4 x4 = *(const float4*)(x + ((size_t)(b * T_ + t0 + r)) * C_ + h * DH + c);
        const unsigned lo = ((unsigned)__builtin_bit_cast(unsigned short, (__bf16)x4.y) << 16)
                          | (unsigned)__builtin_bit_cast(unsigned short, (__bf16)x4.x);
        const unsigned hi = ((unsigned)__builtin_bit_cast(unsigned short, (__bf16)x4.w) << 16)
                          | (unsigned)__builtin_bit_cast(unsigned short, (__bf16)x4.z);
        *(unsigned*)&Xs[r * 72 + c]     = lo;
        *(unsigned*)&Xs[r * 72 + c + 2] = hi;
    }
    // stage weights (fp32 -> bf16): 3 x 1024 float4 chunks
    #pragma unroll
    for (int i = 0; i < 4; ++i) {
        const int idx = i * 256 + tid;
        const int r = idx >> 4, c = (idx & 15) * 4;
        const float* wsrc[3] = {Wq, Wk, Wv};
        #pragma unroll
        for (int wv_ = 0; wv_ < 3; ++wv_) {
            const float4 w4 = *(const float4*)(wsrc[wv_] + r * 64 + c);
            const unsigned lo = ((unsigned)__builtin_bit_cast(unsigned short, (__bf16)w4.y) << 16)
                              | (unsigned)__builtin_bit_cast(unsigned short, (__bf16)w4.x);
            const unsigned hi = ((unsigned)__builtin_bit_cast(unsigned short, (__bf16)w4.w) << 16)
                              | (unsigned)__builtin_bit_cast(unsigned short, (__bf16)w4.z);
            *(unsigned*)&Ws[wv_][r * 72 + c]     = lo;
            *(unsigned*)&Ws[wv_][r * 72 + c + 2] = hi;
        }
    }
    __syncthreads();

    // hoist x A-fragments (wave-private rows 32*wave + m)
    bf16x8 xf[4];
    #pragma unroll
    for (int ks = 0; ks < 4; ++ks)
        xf[ks] = *(const bf16x8*)&Xs[(wave * 32 + m) * 72 + ks * 16 + hh * 8];
    __syncthreads();   // all frag reads done before Vtl aliases Xs

    // 1/sqrt(1024) * log2(e) folded into q (attention uses exp2 directly)
    const float s32 = 0.03125f * 1.4426950408889634f;

    #pragma unroll
    for (int mat = 0; mat < 3; ++mat) {
        f32x16 acc0 = {}, acc1 = {};
        #pragma unroll
        for (int ks = 0; ks < 4; ++ks) {
            const bf16x8 w0 = *(const bf16x8*)&Ws[mat][(m) * 72 + ks * 16 + hh * 8];
            const bf16x8 w1 = *(const bf16x8*)&Ws[mat][(32 + m) * 72 + ks * 16 + hh * 8];
            acc0 = MFMA32(xf[ks], w0, acc0);
            acc1 = MFMA32(xf[ks], w1, acc1);
        }
        const float* bias = (mat == 0) ? bq : (mat == 1) ? bk : bv;
        const float b0 = bias[m], b1 = bias[32 + m];
        #pragma unroll
        for (int r = 0; r < 16; ++r) {
            const int R = (r & 3) + 8 * (r >> 2) + 4 * hh;   // token row in tile
            const int tloc = wave * 32 + R;
            const float v0 = acc0[r] + b0, v1 = acc1[r] + b1;
            if (mat == 0) {
                const size_t base = ((size_t)bh * T_ + t0 + tloc) * DH;
                q[base + m]      = (__bf16)(v0 * s32);
                q[base + 32 + m] = (__bf16)(v1 * s32);
            } else if (mat == 1) {
                const size_t base = ((size_t)bh * T_ + t0 + tloc) * DH;
                k[base + m]      = (__bf16)v0;
                k[base + 32 + m] = (__bf16)v1;
            } else {
                Vtl[(m) * 136 + tloc]      = (__bf16)v0;   // V^T [e][t_local]
                Vtl[(32 + m) * 136 + tloc] = (__bf16)v1;
            }
        }
    }
    __syncthreads();
    // coalesced vt write: 64 e-rows x 128 t (16B chunks; 1024 chunks / 256 thr)
    #pragma unroll
    for (int i = 0; i < 4; ++i) {
        const int idx = i * 256 + tid;
        const int e = idx >> 4, c = (idx & 15) * 8;
        *(uint4*)(vt + ((size_t)(bh * 64 + e)) * T_ + t0 + c) = *(uint4*)&Vtl[e * 136 + c];
    }
}

// ---------------------------------------------------------------------------
// Kernel 2: flash attention, swapped-operand in-register softmax.
// Grid (64 bh, 8 q-tiles): all 8 blocks streaming the same K/V land on ONE
// XCD (linear id mod 8 == bh mod 8) -> K/V stays L2-resident (was 8x HBM
// re-fetch with q-tile on x).
// Block = 256-query tile, 4 waves; each wave owns 64 q-rows. Per kv-tile:
// K and V fragments hoisted ONCE (16 ds_read_b128 per 32 MFMA), then FOUR
// independent (q-half x kv-half) chunks: S(16 regs) -> exp2 -> pack -> PV.
// Independent chains let MFMA / TRANS / LDS pipes overlap (the latency-bound
// fix; previously one serial chain per wave).
// Double-buffered K/V tiles, one barrier per tile; next-tile global loads
// issued before compute. Epilogue: O^T -> LDS -> coalesced 16B stores.
// ---------------------------------------------------------------------------
__global__ __launch_bounds__(256, 2) void attn_kernel(
    const __bf16* __restrict__ q, const __bf16* __restrict__ k,
    const __bf16* __restrict__ vt, __bf16* __restrict__ o)
{
    __shared__ __bf16 smem[2][2][64 * 72];   // [buf][K=0/V^T=1][row][d], 36.9 KB

    const int bh  = blockIdx.x;              // XCD-locality axis
    const int q0  = blockIdx.y * 256;
    const int tid = threadIdx.x;
    const int wave = tid >> 6, lane = tid & 63;
    const int m = lane & 31, h = lane >> 5;

    const __bf16* qb = q  + (size_t)bh * T_ * DH;
    const __bf16* kb = k  + (size_t)bh * T_ * DH;
    const __bf16* vb = vt + (size_t)bh * DH * T_;

    // Q fragments straight from global: 2 halves x 4 ks (one-time, L2-served)
    bf16x8 qf[2][4];
    #pragma unroll
    for (int hf = 0; hf < 2; ++hf)
        #pragma unroll
        for (int ks = 0; ks < 4; ++ks)
            qf[hf][ks] = *(const bf16x8*)(qb +
                (size_t)(q0 + wave * 64 + hf * 32 + m) * DH + ks * 16 + h * 8);

    // staging geometry: 256 threads cover 64x64 bf16 in 2 uint4 each
    const int r0s = tid >> 3;           // 0..31
    const int c0s = (tid & 7) * 8;      // 0,8,..,56

    uint4 kreg[2], vreg[2];
    #pragma unroll
    for (int i = 0; i < 2; ++i) {
        kreg[i] = *(const uint4*)(kb + (size_t)(r0s + 32 * i) * DH + c0s);
        vreg[i] = *(const uint4*)(vb + (size_t)(r0s + 32 * i) * T_ + c0s);
    }
    #pragma unroll
    for (int i = 0; i < 2; ++i) {
        *(uint4*)&smem[0][0][(r0s + 32 * i) * 72 + c0s] = kreg[i];
        *(uint4*)&smem[0][1][(r0s + 32 * i) * 72 + c0s] = vreg[i];
    }

    f32x16 O00 = {}, O01 = {}, O10 = {}, O11 = {};   // [q-half][d-half], O^T [d][q]
    float ls0 = 0.f, ls1 = 0.f;

    int cur = 0;
    for (int kt = 0; kt < T_; kt += 64) {
        __syncthreads();                       // buf[cur] fully staged
        const bool pre = (kt + 64 < T_);
        if (pre) {                             // issue next-tile loads now
            #pragma unroll
            for (int i = 0; i < 2; ++i) {
                kreg[i] = *(const uint4*)(kb + (size_t)(kt + 64 + r0s + 32 * i) * DH + c0s);
                vreg[i] = *(const uint4*)(vb + (size_t)(r0s + 32 * i) * T_ + kt + 64 + c0s);
            }
        }
        const __bf16* Ksb  = &smem[cur][0][0];
        const __bf16* Vtsb = &smem[cur][1][0];

        // hoist K and V fragments ONCE per tile (16 ds_read_b128 total)
        bf16x8 kf[2][4], vf[2][4];
        #pragma unroll
        for (int rh = 0; rh < 2; ++rh)
            #pragma unroll
            for (int ks = 0; ks < 4; ++ks)
                kf[rh][ks] = *(const bf16x8*)&Ksb[(rh * 32 + m) * 72 + ks * 16 + h * 8];
        #pragma unroll
        for (int dh = 0; dh < 2; ++dh)
            #pragma unroll
            for (int c = 0; c < 4; ++c)
                vf[dh][c] = *(const bf16x8*)&Vtsb[(dh * 32 + m) * 72 + c * 16 + h * 8];

        // 4 independent (q-half, kv-half) chunks
        #pragma unroll
        for (int hf = 0; hf < 2; ++hf) {
            float lsum = 0.f;
            #pragma unroll
            for (int rh = 0; rh < 2; ++rh) {
                // S^T chunk: kv rows rh*32.., 32 q-cols
                f32x16 S = {};
                #pragma unroll
                for (int ks = 0; ks < 4; ++ks)
                    S = MFMA32(kf[rh][ks], qf[hf][ks], S);

                #pragma unroll
                for (int cc = 0; cc < 2; ++cc) {
                    const int rb = cc * 8;
                    float e0 = __builtin_amdgcn_exp2f(S[rb + 0]);
                    float e1 = __builtin_amdgcn_exp2f(S[rb + 1]);
                    float e2 = __builtin_amdgcn_exp2f(S[rb + 2]);
                    float e3 = __builtin_amdgcn_exp2f(S[rb + 3]);
                    float e4 = __builtin_amdgcn_exp2f(S[rb + 4]);
                    float e5 = __builtin_amdgcn_exp2f(S[rb + 5]);
                    float e6 = __builtin_amdgcn_exp2f(S[rb + 6]);
                    float e7 = __builtin_amdgcn_exp2f(S[rb + 7]);
                    lsum += ((e0 + e1) + (e2 + e3)) + ((e4 + e5) + (e6 + e7));
                    unsigned a0 = cvt_pk_bf16(e0, e1);
                    unsigned a1 = cvt_pk_bf16(e2, e3);
                    unsigned b0 = cvt_pk_bf16(e4, e5);
                    unsigned b1 = cvt_pk_bf16(e6, e7);
                    asm("v_permlane32_swap_b32 %0, %1" : "+v"(a0), "+v"(b0));
                    asm("v_permlane32_swap_b32 %0, %1" : "+v"(a1), "+v"(b1));
                    const uint4 pw = {a0, a1, b0, b1};
                    const bf16x8 pb = __builtin_bit_cast(bf16x8, pw);
                    const int c = rh * 2 + cc;      // kv 16-slot
                    if (hf == 0) {
                        O00 = MFMA32(vf[0][c], pb, O00);
                        O01 = MFMA32(vf[1][c], pb, O01);
                    } else {
                        O10 = MFMA32(vf[0][c], pb, O10);
                        O11 = MFMA32(vf[1][c], pb, O11);
                    }
                }
            }
            if (hf == 0) ls0 += lsum; else ls1 += lsum;
        }

        if (pre) {                             // land next tile into buf^1
            #pragma unroll
            for (int i = 0; i < 2; ++i) {
                *(uint4*)&smem[cur ^ 1][0][(r0s + 32 * i) * 72 + c0s] = kreg[i];
                *(uint4*)&smem[cur ^ 1][1][(r0s + 32 * i) * 72 + c0s] = vreg[i];
            }
        }
        cur ^= 1;
    }

    // l[q]: lanes l and l+32 hold complementary kv halves of the same q-row
    ls0 += __shfl_xor(ls0, 32);
    ls1 += __shfl_xor(ls1, 32);
    const float li0 = 1.0f / ls0, li1 = 1.0f / ls1;

    __syncthreads();                            // all K/V reads done; reuse smem
    __bf16* Os = &smem[0][0][0];                // [256 rows][stride 72]

    // O^T -> LDS: lane owns q-rows (wave*64 + m) and (wave*64 + 32 + m).
    // reg r -> d = (r&3) + 8*(r>>2) + 4h: each group of 4 regs = 4 consecutive d.
    #pragma unroll
    for (int g = 0; g < 4; ++g) {
        bf16x4 w00, w01, w10, w11;
        #pragma unroll
        for (int j = 0; j < 4; ++j) {
            w00[j] = (__bf16)(O00[4 * g + j] * li0);
            w01[j] = (__bf16)(O01[4 * g + j] * li0);
            w10[j] = (__bf16)(O10[4 * g + j] * li1);
            w11[j] = (__bf16)(O11[4 * g + j] * li1);
        }
        const int row0 = (wave * 64 + m) * 72;
        const int row1 = (wave * 64 + 32 + m) * 72;
        *(bf16x4*)&Os[row0 + 8 * g + 4 * h]      = w00;
        *(bf16x4*)&Os[row0 + 32 + 8 * g + 4 * h] = w01;
        *(bf16x4*)&Os[row1 + 8 * g + 4 * h]      = w10;
        *(bf16x4*)&Os[row1 + 32 + 8 * g + 4 * h] = w11;
    }
    __syncthreads();

    // fully coalesced store: 256 rows x 64 bf16 = 2048 uint4 / 256 threads
    __bf16* ob = o + ((size_t)bh * T_ + q0) * DH;
    #pragma unroll
    for (int i = 0; i < 8; ++i) {
        const int idx = i * 256 + tid;
        const int r = idx >> 3, c = (idx & 7) * 8;
        *(uint4*)(ob + (size_t)r * DH + c) = *(uint4*)&Os[r * 72 + c];
    }
}

// ---------------------------------------------------------------------------
// Kernel 2.5: Wp fp32 -> bf16 pre-conversion (runs once, ~2 us; output goes
// into the dead q workspace). Removes per-iter cvt VALU + halves B-stage
// bytes in proj (Wp slices were re-staged f32 by all 512 proj blocks).
// ---------------------------------------------------------------------------
__global__ __launch_bounds__(256) void wpconv_kernel(
    const float* __restrict__ Wp, __bf16* __restrict__ Wpb)
{
    const size_t idx = (size_t)(blockIdx.x * 256 + threadIdx.x) * 4;
    const float4 w4 = *(const float4*)(Wp + idx);
    const unsigned lo = ((unsigned)__builtin_bit_cast(unsigned short, (__bf16)w4.y) << 16)
                      | (unsigned)__builtin_bit_cast(unsigned short, (__bf16)w4.x);
    const unsigned hi = ((unsigned)__builtin_bit_cast(unsigned short, (__bf16)w4.w) << 16)
                      | (unsigned)__builtin_bit_cast(unsigned short, (__bf16)w4.z);
    uint2 p; p.x = lo; p.y = hi;
    *(uint2*)(Wpb + idx) = p;
}

// ---------------------------------------------------------------------------
// Kernel 3: output projection, bf16 MFMA. out[tok][e] = A[tok][:] . Wpb[e][:] + bp
// Block = 128 tokens x 128 e-cols; K-chunks of 64 (== one head of A).
// B operand now pre-converted bf16 (16B copies, no cvt).
// ---------------------------------------------------------------------------
__global__ __launch_bounds__(256) void proj_kernel(
    const __bf16* __restrict__ a,      // [bh][t][d]
    const __bf16* __restrict__ Wpb, const float* __restrict__ bp,
    float* __restrict__ out)
{
    __shared__ __bf16 As[128 * 72];
    __shared__ __bf16 Bs[128 * 72];

    const int tb = blockIdx.x, eb = blockIdx.y;
    const int tid = threadIdx.x;
    const int wave = tid >> 6, lane = tid & 63;
    const int m = lane & 31, h = lane >> 5;
    const int tok0 = tb * 128;
    const int b = tok0 >> 11, t0 = tok0 & (T_ - 1);
    const int e0 = eb * 128;

    f32x16 acc[4] = {f32x16{}, f32x16{}, f32x16{}, f32x16{}};

    for (int cb = 0; cb < 16; ++cb) {
        __syncthreads();
        // As: 128 rows x 64 bf16 (head cb of A), direct bf16 copy
        #pragma unroll
        for (int i = 0; i < 4; ++i) {
            const int idx = i * 256 + tid;
            const int r = idx >> 3, c = (idx & 7) * 8;
            *(uint4*)&As[r * 72 + c] =
                *(const uint4*)(a + ((size_t)(b * H_ + cb) * T_ + t0 + r) * DH + c);
        }
        // Bs: Wpb rows e0+r, cols cb*64.., direct bf16 copy
        #pragma unroll
        for (int i = 0; i < 4; ++i) {
            const int idx = i * 256 + tid;
            const int r = idx >> 3, c = (idx & 7) * 8;
            *(uint4*)&Bs[r * 72 + c] =
                *(const uint4*)(Wpb + (size_t)(e0 + r) * C_ + cb * 64 + c);
        }
        __syncthreads();

        #pragma unroll
        for (int ks = 0; ks < 4; ++ks) {
            const bf16x8 af = *(const bf16x8*)&As[(wave * 32 + m) * 72 + ks * 16 + h * 8];
            #pragma unroll
            for (int n = 0; n < 4; ++n) {
                const bf16x8 bf = *(const bf16x8*)&Bs[(n * 32 + m) * 72 + ks * 16 + h * 8];
                acc[n] = MFMA32(af, bf, acc[n]);
            }
        }
    }

    #pragma unroll
    for (int n = 0; n < 4; ++n) {
        const int e = e0 + n * 32 + m;
        const float bias = bp[e];
        #pragma unroll
        for (int r = 0; r < 16; ++r) {
            const int R = (r & 3) + 8 * (r >> 2) + 4 * h;
            out[(size_t)(tok0 + wave * 32 + R) * C_ + e] = acc[n][r] + bias;
        }
    }
}

// ---------------------------------------------------------------------------
// Workspace (bf16): q | k | vt | attn_out, each B*H*T*DH = 8388608 elems
// -> 64 MiB total. Wpb (2 MiB) reuses the q region (dead after attn).
// ---------------------------------------------------------------------------
extern "C" void kernel_launch(void* const* d_in, const int* in_sizes, int n_in,
                              void* d_out, int out_size, void* d_ws, size_t ws_size,
                              hipStream_t stream)
{
    const float* x  = (const float*)d_in[0];
    const float* Wq = (const float*)d_in[1];
    const float* bq = (const float*)d_in[2];
    const float* Wk = (const float*)d_in[3];
    const float* bk = (const float*)d_in[4];
    const float* Wv = (const float*)d_in[5];
    const float* bv = (const float*)d_in[6];
    const float* Wp = (const float*)d_in[7];
    const float* bp = (const float*)d_in[8];

    const size_t N = (size_t)BH * T_ * DH;
    __bf16* qws  = (__bf16*)d_ws;
    __bf16* kws  = qws + N;
    __bf16* vtws = kws + N;
    __bf16* ows  = vtws + N;
    __bf16* wpb  = qws;                 // q dead after attn; 2 MiB needed

    qkv_kernel<<<dim3(16, 64), 256, 0, stream>>>(
        x, Wq, bq, Wk, bk, Wv, bv, qws, kws, vtws);
    attn_kernel<<<dim3(64, 8), 256, 0, stream>>>(qws, kws, vtws, ows);
    wpconv_kernel<<<dim3(1024), 256, 0, stream>>>(Wp, wpb);
    proj_kernel<<<dim3(64, 8), 256, 0, stream>>>(ows, wpb, bp, (float*)d_out);
}